// Round 5
// baseline (59.287 us; speedup 1.0000x reference)
//
#include <hip/hip_runtime.h>
#include <math.h>

#define BB 4
#define NN 5
#define CC_DIM 64
#define HH 100
#define WW 252
#define HW (HH * WW)
#define CPT 8              // channels per thread
#define NCHUNK (CC_DIM / CPT)  // 8 chunks

__global__ __launch_bounds__(256) void where2comm_fuse_kernel(
    const float* __restrict__ x,    // (B*N, C, H, W)
    const float* __restrict__ ptm,  // (B, N, N, 2, 3)
    float* __restrict__ out)        // (B, C, H, W) + 1 scalar
{
    const int idx = blockIdx.x * blockDim.x + threadIdx.x;
    const int total = BB * NCHUNK * HH * WW;   // 806400
    if (idx >= total) {
        return;
    }

    // decompose: w fastest (coalescing), then h, then channel-chunk, then b
    int w = idx % WW;
    int t = idx / WW;
    int h = t % HH;
    t /= HH;
    int cc = t % NCHUNK;
    int b = t / NCHUNK;

    const float gx = (2.0f * (float)w + 1.0f) / (float)WW - 1.0f;
    const float gy = (2.0f * (float)h + 1.0f) / (float)HH - 1.0f;

    const float* th_b = ptm + (size_t)b * (NN * NN * 6);

    // Per-agent: base pointer of the 2x2 loaded patch (rows rl,rl+1, cols cl,cl+1)
    // and the 4 effective weights g[row][col] applied to the loaded values.
    const float* pbase[NN];
    float g00[NN], g01[NN], g10[NN], g11[NN];

#pragma unroll
    for (int n = 0; n < NN; ++n) {
        const float t00 = th_b[n * 6 + 0];
        const float t01 = th_b[n * 6 + 1];
        const float t02 = th_b[n * 6 + 2];
        const float t10 = th_b[n * 6 + 3];
        const float t11 = th_b[n * 6 + 4];
        const float t12 = th_b[n * 6 + 5];

        const float cx = t00 * gx + t01 * gy + t02;
        const float cy = t10 * gx + t11 * gy + t12;

        const float ix = ((cx + 1.0f) * (float)WW - 1.0f) * 0.5f;
        const float iy = ((cy + 1.0f) * (float)HH - 1.0f) * 0.5f;

        const float x0f = floorf(ix);
        const float y0f = floorf(iy);
        const float x1f = x0f + 1.0f;
        const float y1f = y0f + 1.0f;

        const float wx1 = ix - x0f;
        const float wx0 = 1.0f - wx1;
        const float wy1 = iy - y0f;
        const float wy0 = 1.0f - wy1;

        // validity per corner (zero-padding semantics)
        const float mx0 = (x0f >= 0.0f && x0f <= (float)(WW - 1)) ? 1.0f : 0.0f;
        const float mx1 = (x1f >= 0.0f && x1f <= (float)(WW - 1)) ? 1.0f : 0.0f;
        const float my0 = (y0f >= 0.0f && y0f <= (float)(HH - 1)) ? 1.0f : 0.0f;
        const float my1 = (y1f >= 0.0f && y1f <= (float)(HH - 1)) ? 1.0f : 0.0f;

        // effective corner weights
        const float e00 = wx0 * wy0 * mx0 * my0;
        const float e10 = wx1 * wy0 * mx1 * my0;
        const float e01 = wx0 * wy1 * mx0 * my1;
        const float e11 = wx1 * wy1 * mx1 * my1;

        // clamped corner indices (reference semantics)
        const int xi0 = (int)fminf(fmaxf(x0f, 0.0f), (float)(WW - 1));
        const int xi1 = (int)fminf(fmaxf(x1f, 0.0f), (float)(WW - 1));
        const int yi0 = (int)fminf(fmaxf(y0f, 0.0f), (float)(HH - 1));
        const int yi1 = (int)fminf(fmaxf(y1f, 0.0f), (float)(HH - 1));

        // loaded 2x2 patch origin — always fully in-bounds
        const int cl = (int)fminf(fmaxf(x0f, 0.0f), (float)(WW - 2));
        const int rl = (int)fminf(fmaxf(y0f, 0.0f), (float)(HH - 2));

        // element-position of each corner within the loaded patch (0 or 1).
        // OOB corners have weight 0, so their routing is don't-care.
        const float sx0 = (float)(xi0 - cl);
        const float sx1 = (float)(xi1 - cl);
        const float sy0 = (float)(yi0 - rl);
        const float sy1 = (float)(yi1 - rl);
        const float nx0 = 1.0f - sx0, nx1 = 1.0f - sx1;
        const float ny0 = 1.0f - sy0, ny1 = 1.0f - sy1;

        // route each corner's weight to the patch element it samples
        g00[n] = e00 * nx0 * ny0 + e10 * nx1 * ny0 + e01 * nx0 * ny1 + e11 * nx1 * ny1;
        g01[n] = e00 * sx0 * ny0 + e10 * sx1 * ny0 + e01 * sx0 * ny1 + e11 * sx1 * ny1;
        g10[n] = e00 * nx0 * sy0 + e10 * nx1 * sy0 + e01 * nx0 * sy1 + e11 * nx1 * sy1;
        g11[n] = e00 * sx0 * sy0 + e10 * sx1 * sy0 + e01 * sx0 * sy1 + e11 * sx1 * sy1;

        pbase[n] = x + ((size_t)(b * NN + n) * CC_DIM + cc * CPT) * HW + rl * WW + cl;
    }

    float acc[CPT];
#pragma unroll
    for (int c = 0; c < CPT; ++c) acc[c] = -INFINITY;

#pragma unroll
    for (int c = 0; c < CPT; ++c) {
        // issue all 10 pair-loads (5 agents x 2 rows) for this channel
        float lo[NN][2], hi[NN][2];
#pragma unroll
        for (int n = 0; n < NN; ++n) {
            const float* p = pbase[n] + (size_t)c * HW;
            __builtin_memcpy(&lo[n][0], p, 8);        // row rl:   cols cl, cl+1
            __builtin_memcpy(&hi[n][0], p + WW, 8);   // row rl+1: cols cl, cl+1
        }
        // consume
#pragma unroll
        for (int n = 0; n < NN; ++n) {
            float v = lo[n][0] * g00[n];
            v = fmaf(lo[n][1], g01[n], v);
            v = fmaf(hi[n][0], g10[n], v);
            v = fmaf(hi[n][1], g11[n], v);
            acc[c] = fmaxf(acc[c], v);
        }
    }

    // write outputs: out[b, cc*CPT + c, h, w]
#pragma unroll
    for (int c = 0; c < CPT; ++c) {
        out[(((size_t)b * CC_DIM + cc * CPT + c) * HH + h) * WW + w] = acc[c];
    }

    if (idx == 0) {
        out[(size_t)BB * CC_DIM * HW] = 0.0f;  // communication_rates
    }
}

extern "C" void kernel_launch(void* const* d_in, const int* in_sizes, int n_in,
                              void* d_out, int out_size, void* d_ws, size_t ws_size,
                              hipStream_t stream) {
    const float* x = (const float*)d_in[0];
    const float* ptm = (const float*)d_in[3];
    float* out = (float*)d_out;

    const int total = BB * NCHUNK * HH * WW;  // 806400
    const int block = 256;
    const int grid = (total + block - 1) / block;  // 3150
    where2comm_fuse_kernel<<<grid, block, 0, stream>>>(x, ptm, out);
}